// Round 2
// baseline (755.120 us; speedup 1.0000x reference)
//
#include <hip/hip_runtime.h>

// LightGCN 3-layer propagation. out layout: [4, N_NODES, DIM] f32.
//   layer 0 = embeddings (copy); layer l = SpMM(layer l-1).
//
// R5 design:
//  - CSR build via two-pass bucketing. R4 showed node-granular scatter cannot
//    merge lines (a node's line fills over the whole kernel; evicted first).
//    pass1 scatters into 64-node buckets: per-bucket SEQUENTIAL write streams,
//    range-partitioned (r=blockIdx%8) so each bucket stream is single-XCD and
//    its active line fills in ~0.2us -> full L2 merging (WRITE ~ 9.6 MB).
//  - pass2: one block per bucket sorts its ~6KB region via LDS counters, and
//    emits deg/off directly (replaces node hist + 3 scan kernels).
//  - spmm: oct scheme, 8 independent edge gather chains per wave (was 4).

#define N_NODES 100000
#define DIM 64

#define BSH 6                               // bucket = 64 nodes
#define NBK ((N_NODES + 63) >> 6)           // 1563 buckets
#define NR 8                                // dst ranges (XCD heuristic)
#define BPR ((NBK + NR - 1) / NR)           // 196 buckets per range
#define RSIZE (BPR << BSH)                  // 12544 nodes per range (bucket-aligned)
#define SLICES 256                          // edge slices for pass1

#define SCAN_CHUNK 1024                     // (legacy mid-path scan)

// ---------------- path A: bucketed two-pass CSR build ----------------

// Bucket histogram: vectorized single pass over edst.
__global__ void bhist_kernel(const int* __restrict__ edst, int* __restrict__ bcnt, int E) {
    int i = blockIdx.x * blockDim.x + threadIdx.x;
    int nv = E >> 2;
    if (i < nv) {
        int4 d = ((const int4*)edst)[i];
        atomicAdd(&bcnt[d.x >> BSH], 1);
        atomicAdd(&bcnt[d.y >> BSH], 1);
        atomicAdd(&bcnt[d.z >> BSH], 1);
        atomicAdd(&bcnt[d.w >> BSH], 1);
    }
    if (i == 0) {
        for (int e = nv << 2; e < E; ++e) atomicAdd(&bcnt[edst[e] >> BSH], 1);
    }
}

// Single-block exclusive scan of NBK (<2048) bucket counts -> bbase, bcur.
__global__ void bscan_kernel(const int* __restrict__ bcnt, int* __restrict__ bbase,
                             int* __restrict__ bcur, int nbk) {
    __shared__ int s[1024];
    int t = threadIdx.x;
    int i0 = 2 * t, i1 = 2 * t + 1;
    int v0 = (i0 < nbk) ? bcnt[i0] : 0;
    int v1 = (i1 < nbk) ? bcnt[i1] : 0;
    s[t] = v0 + v1;
    __syncthreads();
    for (int d = 1; d < 1024; d <<= 1) {
        int tt = (t >= d) ? s[t - d] : 0;
        __syncthreads();
        s[t] += tt;
        __syncthreads();
    }
    int excl = s[t] - (v0 + v1);
    if (i0 < nbk) { bbase[i0] = excl;      bcur[i0] = excl; }
    if (i1 < nbk) { bbase[i1] = excl + v0; bcur[i1] = excl + v0; }
    if (t == 1023) bbase[nbk] = s[1023];
}

// pass1: block (r=blockIdx%8, s=blockIdx/8) scans edge slice s, keeps edges
// with dst in range r, appends {src|dlocal<<20, w} to the dst's bucket stream.
// Sequential per-bucket streams + single-XCD ownership -> lines merge in L2.
__global__ void pass1_kernel(const int* __restrict__ esrc, const int* __restrict__ edst,
                             const float* __restrict__ ew, int* __restrict__ bcur,
                             int2* __restrict__ tmp, int E, int chunk) {
    const int r = blockIdx.x & (NR - 1);
    const int s = blockIdx.x / NR;
    const int lo = r * RSIZE;
    const int hi = min(lo + RSIZE, N_NODES);
    const int e0 = s * chunk;
    if (e0 >= E) return;
    const int e1 = min(e0 + chunk, E);
    const int nv = (e1 - e0) >> 2;
    const int4*   s4 = (const int4*)(esrc + e0);
    const int4*   d4 = (const int4*)(edst + e0);
    const float4* w4 = (const float4*)(ew + e0);
    for (int i = threadIdx.x; i < nv; i += blockDim.x) {
        int4 dd = d4[i]; int4 ss = s4[i]; float4 ww = w4[i];
        #pragma unroll
        for (int j = 0; j < 4; ++j) {
            int d = (j == 0) ? dd.x : (j == 1) ? dd.y : (j == 2) ? dd.z : dd.w;
            if (d >= lo && d < hi) {
                int src = (j == 0) ? ss.x : (j == 1) ? ss.y : (j == 2) ? ss.z : ss.w;
                float w = (j == 0) ? ww.x : (j == 1) ? ww.y : (j == 2) ? ww.z : ww.w;
                int b = d >> BSH;
                int p = atomicAdd(&bcur[b], 1);   // bcur pre-seeded with bbase
                int2 pr;
                pr.x = src | ((d & 63) << 20);
                pr.y = __float_as_int(w);
                tmp[p] = pr;
            }
        }
    }
    for (int e = e0 + (nv << 2) + threadIdx.x; e < e1; e += blockDim.x) {
        int d = edst[e];
        if (d >= lo && d < hi) {
            int b = d >> BSH;
            int p = atomicAdd(&bcur[b], 1);
            int2 pr;
            pr.x = esrc[e] | ((d & 63) << 20);
            pr.y = __float_as_int(ew[e]);
            tmp[p] = pr;
        }
    }
}

// pass2: one block per bucket. Count per-node degrees (LDS), wave-scan 64
// values, emit deg/off, then place edges at final CSR positions. Writes land
// in the block's own ~6KB region (single XCD, hot in L2) -> merge fine.
__global__ void pass2_kernel(const int2* __restrict__ tmp, const int* __restrict__ bbase,
                             int2* __restrict__ pairs, int* __restrict__ deg,
                             int* __restrict__ off) {
    __shared__ int lpos[64];
    __shared__ int ldeg[64];
    const int b = blockIdx.x;
    const int base = bbase[b];
    const int n = bbase[b + 1] - base;
    if (threadIdx.x < 64) ldeg[threadIdx.x] = 0;
    __syncthreads();
    for (int i = threadIdx.x; i < n; i += blockDim.x) {
        atomicAdd(&ldeg[tmp[base + i].x >> 20], 1);
    }
    __syncthreads();
    if (threadIdx.x < 64) {
        int v = ldeg[threadIdx.x];
        int p = v;
        #pragma unroll
        for (int d = 1; d < 64; d <<= 1) {
            int t = __shfl_up(p, d);
            if (threadIdx.x >= d) p += t;
        }
        int excl = p - v;                     // exclusive prefix within bucket
        lpos[threadIdx.x] = excl;
        int node = (b << BSH) + threadIdx.x;
        if (node < N_NODES) { deg[node] = v; off[node] = base + excl; }
    }
    __syncthreads();
    for (int i = threadIdx.x; i < n; i += blockDim.x) {
        int2 pr = tmp[base + i];
        int dl = pr.x >> 20;
        int p = base + atomicAdd(&lpos[dl], 1);
        pr.x &= 0xFFFFF;                      // strip dlocal -> pure src
        pairs[p] = pr;
    }
}

// ---------------- SpMM: one wave per node, 8 edges in flight ----------------
// Oct o (lanes 8o..8o+7) processes edges k = o, o+8, ... Each lane loads
// row[ol] and row[ol+8] (2x float4, 256B/oct). Cross-oct sum via shfl_xor.

__global__ void spmm_csr_kernel(const float* __restrict__ x,
                                const int2* __restrict__ pairs,
                                const int* __restrict__ off,
                                const int* __restrict__ deg,
                                float* __restrict__ y) {
    int gtid = blockIdx.x * blockDim.x + threadIdx.x;
    int node = gtid >> 6;
    int lane = threadIdx.x & 63;
    int o  = lane >> 3;    // oct 0..7 = which edge in the group of 8
    int ol = lane & 7;     // lane within oct
    if (node >= N_NODES) return;
    int s0 = off[node];
    int n  = deg[node];
    float4 a0 = make_float4(0.f, 0.f, 0.f, 0.f);
    float4 a1 = make_float4(0.f, 0.f, 0.f, 0.f);
    for (int k = o; k < n; k += 8) {
        int2 pr = pairs[s0 + k];                 // uniform within oct
        float w = __int_as_float(pr.y);
        const float4* row = (const float4*)(x + (size_t)pr.x * DIM);
        float4 v0 = row[ol];                     // dims [4ol, 4ol+4)
        float4 v1 = row[ol + 8];                 // dims [32+4ol, 32+4ol+4)
        a0.x += w * v0.x; a0.y += w * v0.y; a0.z += w * v0.z; a0.w += w * v0.w;
        a1.x += w * v1.x; a1.y += w * v1.y; a1.z += w * v1.z; a1.w += w * v1.w;
    }
    #pragma unroll
    for (int d = 8; d <= 32; d <<= 1) {
        a0.x += __shfl_xor(a0.x, d); a0.y += __shfl_xor(a0.y, d);
        a0.z += __shfl_xor(a0.z, d); a0.w += __shfl_xor(a0.w, d);
        a1.x += __shfl_xor(a1.x, d); a1.y += __shfl_xor(a1.y, d);
        a1.z += __shfl_xor(a1.z, d); a1.w += __shfl_xor(a1.w, d);
    }
    if (o == 0) {
        float4* yrow = (float4*)(y + (size_t)node * DIM);
        yrow[ol]     = a0;
        yrow[ol + 8] = a1;
    }
}

// ---------------- path B: legacy single-buffer CSR build ----------------

__global__ void hist_kernel(const int* __restrict__ edst, int* __restrict__ deg, int E) {
    int e = blockIdx.x * blockDim.x + threadIdx.x;
    if (e < E) atomicAdd(&deg[edst[e]], 1);
}

__global__ void scan1_kernel(const int* __restrict__ deg, int* __restrict__ off,
                             int* __restrict__ bsum, int n) {
    __shared__ int sdata[256];
    int tid = threadIdx.x;
    int base = blockIdx.x * SCAN_CHUNK + tid * 4;
    int v[4];
    #pragma unroll
    for (int i = 0; i < 4; ++i) v[i] = (base + i < n) ? deg[base + i] : 0;
    int tsum = v[0] + v[1] + v[2] + v[3];
    sdata[tid] = tsum;
    __syncthreads();
    for (int d = 1; d < 256; d <<= 1) {
        int t = (tid >= d) ? sdata[tid - d] : 0;
        __syncthreads();
        sdata[tid] += t;
        __syncthreads();
    }
    int excl = sdata[tid] - tsum;
    if (tid == 255) bsum[blockIdx.x] = sdata[255];
    int run = excl;
    #pragma unroll
    for (int i = 0; i < 4; ++i) {
        if (base + i < n) off[base + i] = run;
        run += v[i];
    }
}

__global__ void scan2_kernel(int* __restrict__ bsum, int nb) {
    __shared__ int s[128];
    int tid = threadIdx.x;
    int v = (tid < nb) ? bsum[tid] : 0;
    s[tid] = v;
    __syncthreads();
    for (int d = 1; d < 128; d <<= 1) {
        int t = (tid >= d) ? s[tid - d] : 0;
        __syncthreads();
        s[tid] += t;
        __syncthreads();
    }
    if (tid < nb) bsum[tid] = s[tid] - v;
}

__global__ void scan3_kernel(int* __restrict__ off, const int* __restrict__ bsum, int n) {
    int i = blockIdx.x * blockDim.x + threadIdx.x;
    if (i < n) off[i] += bsum[i / SCAN_CHUNK];
}

__global__ void scatter_kernel(const int* __restrict__ esrc, const int* __restrict__ edst,
                               const float* __restrict__ ew, const int* __restrict__ off,
                               int* __restrict__ cur, int2* __restrict__ pairs, int E) {
    int e = blockIdx.x * blockDim.x + threadIdx.x;
    if (e >= E) return;
    int d = edst[e];
    int p = off[d] + atomicAdd(&cur[d], 1);
    int2 pr;
    pr.x = esrc[e];
    pr.y = __float_as_int(ew[e]);
    pairs[p] = pr;
}

// ---------------- path C: atomic fallback ----------------

__global__ void spmm_atomic_kernel(const float* __restrict__ x, const float* __restrict__ ew,
                                   const int* __restrict__ esrc, const int* __restrict__ edst,
                                   float* __restrict__ y, int n_edges) {
    long long tid = (long long)blockIdx.x * blockDim.x + threadIdx.x;
    int e = (int)(tid >> 6);
    int d = (int)(tid & 63);
    if (e >= n_edges) return;
    int s = esrc[e]; int t = edst[e]; float w = ew[e];
    atomicAdd(&y[(long long)t * DIM + d], w * x[(long long)s * DIM + d]);
}

extern "C" void kernel_launch(void* const* d_in, const int* in_sizes, int n_in,
                              void* d_out, int out_size, void* d_ws, size_t ws_size,
                              hipStream_t stream) {
    const float* emb  = (const float*)d_in[0];
    const float* ew   = (const float*)d_in[1];
    const int*   esrc = (const int*)d_in[2];
    const int*   edst = (const int*)d_in[3];
    float* out = (float*)d_out;

    const int E = in_sizes[1];
    const size_t layer_elems = (size_t)N_NODES * DIM;

    hipMemcpyAsync(out, emb, layer_elems * sizeof(float), hipMemcpyDeviceToDevice, stream);

    const size_t need_new = (size_t)E * 16 + (size_t)N_NODES * 8 + (size_t)(3 * NBK + 1) * 4 + 1024;
    const size_t need_old = (size_t)E * 8 + (size_t)3 * N_NODES * 4 + 512;

    if (ws_size >= need_new) {
        char* w = (char*)d_ws;
        int2* pairs = (int2*)w;
        int2* tmp   = (int2*)(w + (size_t)E * 8);
        int*  deg   = (int*)(w + (size_t)E * 16);
        int*  off   = deg + N_NODES;
        int*  bcnt  = off + N_NODES;
        int*  bbase = bcnt + NBK;
        int*  bcur  = bbase + NBK + 1;

        hipMemsetAsync(bcnt, 0, (size_t)NBK * 4, stream);

        const int nv = E >> 2;
        bhist_kernel<<<(nv + 255) / 256, 256, 0, stream>>>(edst, bcnt, E);
        bscan_kernel<<<1, 1024, 0, stream>>>(bcnt, bbase, bcur, NBK);

        const int chunk = (((E + SLICES - 1) / SLICES) + 3) & ~3;
        pass1_kernel<<<NR * SLICES, 256, 0, stream>>>(esrc, edst, ew, bcur, tmp, E, chunk);
        pass2_kernel<<<NBK, 256, 0, stream>>>(tmp, bbase, pairs, deg, off);

        const int nb = (N_NODES + 3) / 4;   // 4 waves (nodes) per 256-thread block
        for (int l = 1; l <= 3; ++l) {
            spmm_csr_kernel<<<nb, 256, 0, stream>>>(
                out + (size_t)(l - 1) * layer_elems, pairs, off, deg,
                out + (size_t)l * layer_elems);
        }
    } else if (ws_size >= need_old) {
        char* w = (char*)d_ws;
        int2* pairs = (int2*)w;
        int* deg  = (int*)(w + (size_t)E * 8);
        int* cur  = deg + N_NODES;
        int* off  = cur + N_NODES;
        int* bsum = off + N_NODES;

        hipMemsetAsync(deg, 0, (size_t)2 * N_NODES * 4, stream);

        const int eb = (E + 255) / 256;
        hist_kernel<<<eb, 256, 0, stream>>>(edst, deg, E);

        const int nscan = (N_NODES + SCAN_CHUNK - 1) / SCAN_CHUNK;
        scan1_kernel<<<nscan, 256, 0, stream>>>(deg, off, bsum, N_NODES);
        scan2_kernel<<<1, 128, 0, stream>>>(bsum, nscan);
        scan3_kernel<<<(N_NODES + 255) / 256, 256, 0, stream>>>(off, bsum, N_NODES);

        scatter_kernel<<<eb, 256, 0, stream>>>(esrc, edst, ew, off, cur, pairs, E);

        const int nb = (N_NODES + 3) / 4;
        for (int l = 1; l <= 3; ++l) {
            spmm_csr_kernel<<<nb, 256, 0, stream>>>(
                out + (size_t)(l - 1) * layer_elems, pairs, off, deg,
                out + (size_t)l * layer_elems);
        }
    } else {
        hipMemsetAsync(out + layer_elems, 0, 3 * layer_elems * sizeof(float), stream);
        const long long total_threads = (long long)E * 64;
        const int blocks = (int)((total_threads + 255) / 256);
        for (int l = 1; l <= 3; ++l) {
            spmm_atomic_kernel<<<blocks, 256, 0, stream>>>(
                out + (size_t)(l - 1) * layer_elems, ew, esrc, edst,
                out + (size_t)l * layer_elems, E);
        }
    }
}

// Round 3
// 392.694 us; speedup vs baseline: 1.9229x; 1.9229x over previous
//
#include <hip/hip_runtime.h>

// LightGCN 3-layer propagation. out layout: [4, N_NODES, DIM] f32.
//   layer 0 = embeddings (copy); layer l = SpMM(layer l-1).
//
// History of the build-stage fight (keep for context):
//  R4: node-granular scatter, dst-range partitioned (r=blockIdx%8 ~ XCD).
//      WRITE 77->73 MB only: partial pairs-lines evicted by the ~14 MB/XCD
//      edge-read stream before they fill. Affinity right, eviction wrong.
//  R5: bucket streams to fix temporal fill -> DISASTER (755 us). 1.2M
//      returning atomics over 1563 counters = 768 serialized/addr at ~410 ns
//      each (coherence-point latency). Rule: per-address atomic multiplicity
//      must stay in the tens. bhist had the same disease.
//  R6 (this round): R4 build (100K counters, 12/addr = fine) + NONTEMPORAL
//      edge-stream loads (nt bit: no-allocate in L2) so the range's 1.2 MB
//      pairs region survives in its XCD's L2 for the kernel lifetime ->
//      line merging. NT store of y in spmm to not evict cached x rows.
//      spmm: oct scheme (8 independent gather chains/wave, R5-validated).

#define N_NODES 100000
#define DIM 64
#define SCAN_CHUNK 1024   // elements scanned per block in scan1 (256 thr x 4)

#define NR 8                              // dst ranges (XCD round-robin heuristic)
#define RSIZE ((N_NODES + NR - 1) / NR)   // 12500 nodes per range
#define SLICES 128                        // edge slices per range

typedef int   vint4   __attribute__((ext_vector_type(4)));
typedef float vfloat4 __attribute__((ext_vector_type(4)));

// ---------------- CSR build ----------------

// Range-partitioned histogram. Edge stream read NT (bypass/evict-first in L2)
// so deg's 50 KB stays hot. Atomic multiplicity ~12/node -> uncontended.
__global__ void hist_range_kernel(const int* __restrict__ edst, int* __restrict__ deg,
                                  int E, int chunk) {
    const int r = blockIdx.x & (NR - 1);
    const int s = blockIdx.x / NR;
    const int lo = r * RSIZE;
    const int hi = min(lo + RSIZE, N_NODES);
    const int e0 = s * chunk;
    if (e0 >= E) return;
    const int e1 = min(e0 + chunk, E);
    const int nv = (e1 - e0) >> 2;              // e0, chunk are multiples of 4
    const vint4* d4 = (const vint4*)(edst + e0);
    for (int i = threadIdx.x; i < nv; i += blockDim.x) {
        vint4 d = __builtin_nontemporal_load(d4 + i);
        #pragma unroll
        for (int j = 0; j < 4; ++j) {
            int dj = d[j];
            if (dj >= lo && dj < hi) atomicAdd(&deg[dj], 1);
        }
    }
    for (int e = e0 + (nv << 2) + threadIdx.x; e < e1; e += blockDim.x) {
        int dj = edst[e];
        if (dj >= lo && dj < hi) atomicAdd(&deg[dj], 1);
    }
}

// Per-block exclusive scan over chunks of 1024; emits per-block totals.
__global__ void scan1_kernel(const int* __restrict__ deg, int* __restrict__ off,
                             int* __restrict__ bsum, int n) {
    __shared__ int sdata[256];
    int tid = threadIdx.x;
    int base = blockIdx.x * SCAN_CHUNK + tid * 4;
    int v[4];
    #pragma unroll
    for (int i = 0; i < 4; ++i) v[i] = (base + i < n) ? deg[base + i] : 0;
    int tsum = v[0] + v[1] + v[2] + v[3];
    sdata[tid] = tsum;
    __syncthreads();
    for (int d = 1; d < 256; d <<= 1) {
        int t = (tid >= d) ? sdata[tid - d] : 0;
        __syncthreads();
        sdata[tid] += t;
        __syncthreads();
    }
    int excl = sdata[tid] - tsum;
    if (tid == 255) bsum[blockIdx.x] = sdata[255];
    int run = excl;
    #pragma unroll
    for (int i = 0; i < 4; ++i) {
        if (base + i < n) off[base + i] = run;
        run += v[i];
    }
}

// Single-block 128-thread exclusive scan of the block sums (nb <= 128).
__global__ void scan2_kernel(int* __restrict__ bsum, int nb) {
    __shared__ int s[128];
    int tid = threadIdx.x;
    int v = (tid < nb) ? bsum[tid] : 0;
    s[tid] = v;
    __syncthreads();
    for (int d = 1; d < 128; d <<= 1) {
        int t = (tid >= d) ? s[tid - d] : 0;
        __syncthreads();
        s[tid] += t;
        __syncthreads();
    }
    if (tid < nb) bsum[tid] = s[tid] - v;   // exclusive
}

__global__ void scan3_kernel(int* __restrict__ off, const int* __restrict__ bsum, int n) {
    int i = blockIdx.x * blockDim.x + threadIdx.x;
    if (i < n) off[i] += bsum[i / SCAN_CHUNK];
}

// Range-partitioned scatter. Edge streams (esrc/edst/ew) read NT so the
// range's ~1.2 MB pairs region + 50 KB cur/off stay L2-resident for the
// whole kernel -> partial 8 B writes merge into full-line writebacks.
__global__ void scatter_range_kernel(const int* __restrict__ esrc, const int* __restrict__ edst,
                                     const float* __restrict__ ew, const int* __restrict__ off,
                                     int* __restrict__ cur, int2* __restrict__ pairs,
                                     int E, int chunk) {
    const int r = blockIdx.x & (NR - 1);
    const int s = blockIdx.x / NR;
    const int lo = r * RSIZE;
    const int hi = min(lo + RSIZE, N_NODES);
    const int e0 = s * chunk;
    if (e0 >= E) return;
    const int e1 = min(e0 + chunk, E);
    const int nv = (e1 - e0) >> 2;
    const vint4*   s4 = (const vint4*)(esrc + e0);
    const vint4*   d4 = (const vint4*)(edst + e0);
    const vfloat4* w4 = (const vfloat4*)(ew + e0);
    for (int i = threadIdx.x; i < nv; i += blockDim.x) {
        vint4 dd = __builtin_nontemporal_load(d4 + i);
        vint4 ss = __builtin_nontemporal_load(s4 + i);
        vfloat4 ww = __builtin_nontemporal_load(w4 + i);
        #pragma unroll
        for (int j = 0; j < 4; ++j) {
            int dj = dd[j];
            if (dj >= lo && dj < hi) {
                int p = off[dj] + atomicAdd(&cur[dj], 1);
                int2 pr;
                pr.x = ss[j];
                pr.y = __float_as_int(ww[j]);
                pairs[p] = pr;
            }
        }
    }
    for (int e = e0 + (nv << 2) + threadIdx.x; e < e1; e += blockDim.x) {
        int dj = edst[e];
        if (dj >= lo && dj < hi) {
            int p = off[dj] + atomicAdd(&cur[dj], 1);
            int2 pr;
            pr.x = esrc[e];
            pr.y = __float_as_int(ew[e]);
            pairs[p] = pr;
        }
    }
}

// ---------------- SpMM: one wave per node, 8 edges in flight ----------------
// Oct o (lanes 8o..8o+7) processes edges k = o, o+8, ... Each lane loads
// row[ol] and row[ol+8] (2x float4 = 256 B/oct). Cross-oct sum via shfl_xor.
// y stored NT (written once; don't evict cached x rows).

__global__ void spmm_csr_kernel(const float* __restrict__ x,
                                const int2* __restrict__ pairs,
                                const int* __restrict__ off,
                                const int* __restrict__ deg,
                                float* __restrict__ y) {
    int gtid = blockIdx.x * blockDim.x + threadIdx.x;
    int node = gtid >> 6;
    int lane = threadIdx.x & 63;
    int o  = lane >> 3;    // oct 0..7 = which edge in the group of 8
    int ol = lane & 7;     // lane within oct
    if (node >= N_NODES) return;
    int s0 = off[node];
    int n  = deg[node];
    float4 a0 = make_float4(0.f, 0.f, 0.f, 0.f);
    float4 a1 = make_float4(0.f, 0.f, 0.f, 0.f);
    for (int k = o; k < n; k += 8) {
        int2 pr = pairs[s0 + k];                 // uniform within oct
        float w = __int_as_float(pr.y);
        const float4* row = (const float4*)(x + (size_t)pr.x * DIM);
        float4 v0 = row[ol];                     // dims [4ol, 4ol+4)
        float4 v1 = row[ol + 8];                 // dims [32+4ol, ...)
        a0.x += w * v0.x; a0.y += w * v0.y; a0.z += w * v0.z; a0.w += w * v0.w;
        a1.x += w * v1.x; a1.y += w * v1.y; a1.z += w * v1.z; a1.w += w * v1.w;
    }
    #pragma unroll
    for (int d = 8; d <= 32; d <<= 1) {
        a0.x += __shfl_xor(a0.x, d); a0.y += __shfl_xor(a0.y, d);
        a0.z += __shfl_xor(a0.z, d); a0.w += __shfl_xor(a0.w, d);
        a1.x += __shfl_xor(a1.x, d); a1.y += __shfl_xor(a1.y, d);
        a1.z += __shfl_xor(a1.z, d); a1.w += __shfl_xor(a1.w, d);
    }
    if (o == 0) {
        vfloat4* yrow = (vfloat4*)(y + (size_t)node * DIM);
        vfloat4 r0 = { a0.x, a0.y, a0.z, a0.w };
        vfloat4 r1 = { a1.x, a1.y, a1.z, a1.w };
        __builtin_nontemporal_store(r0, yrow + ol);
        __builtin_nontemporal_store(r1, yrow + ol + 8);
    }
}

// ---------------- fallback (atomic path, if ws too small) ----------------

__global__ void spmm_atomic_kernel(const float* __restrict__ x, const float* __restrict__ ew,
                                   const int* __restrict__ esrc, const int* __restrict__ edst,
                                   float* __restrict__ y, int n_edges) {
    long long tid = (long long)blockIdx.x * blockDim.x + threadIdx.x;
    int e = (int)(tid >> 6);
    int d = (int)(tid & 63);
    if (e >= n_edges) return;
    int s = esrc[e]; int t = edst[e]; float w = ew[e];
    atomicAdd(&y[(long long)t * DIM + d], w * x[(long long)s * DIM + d]);
}

extern "C" void kernel_launch(void* const* d_in, const int* in_sizes, int n_in,
                              void* d_out, int out_size, void* d_ws, size_t ws_size,
                              hipStream_t stream) {
    const float* emb  = (const float*)d_in[0];
    const float* ew   = (const float*)d_in[1];
    const int*   esrc = (const int*)d_in[2];
    const int*   edst = (const int*)d_in[3];
    float* out = (float*)d_out;

    const int E = in_sizes[1];
    const size_t layer_elems = (size_t)N_NODES * DIM;

    size_t need = (size_t)E * 8 + (size_t)3 * N_NODES * 4 + 512;
    hipMemcpyAsync(out, emb, layer_elems * sizeof(float), hipMemcpyDeviceToDevice, stream);

    if (ws_size >= need) {
        char* w = (char*)d_ws;
        int2* pairs = (int2*)w;
        int* deg  = (int*)(w + (size_t)E * 8);
        int* cur  = deg + N_NODES;
        int* off  = cur + N_NODES;
        int* bsum = off + N_NODES;

        hipMemsetAsync(deg, 0, (size_t)2 * N_NODES * 4, stream);

        // edge slice size: multiple of 4 so vint4 loads stay aligned
        const int chunk = (((E + SLICES - 1) / SLICES) + 3) & ~3;
        const int rblocks = NR * SLICES;   // 1024 blocks; blockIdx%8 = range

        hist_range_kernel<<<rblocks, 256, 0, stream>>>(edst, deg, E, chunk);

        const int nscan = (N_NODES + SCAN_CHUNK - 1) / SCAN_CHUNK;   // 98
        scan1_kernel<<<nscan, 256, 0, stream>>>(deg, off, bsum, N_NODES);
        scan2_kernel<<<1, 128, 0, stream>>>(bsum, nscan);
        scan3_kernel<<<(N_NODES + 255) / 256, 256, 0, stream>>>(off, bsum, N_NODES);

        scatter_range_kernel<<<rblocks, 256, 0, stream>>>(esrc, edst, ew, off, cur, pairs, E, chunk);

        const int nb = (N_NODES + 3) / 4;   // 4 waves (nodes) per 256-thread block
        for (int l = 1; l <= 3; ++l) {
            spmm_csr_kernel<<<nb, 256, 0, stream>>>(
                out + (size_t)(l - 1) * layer_elems, pairs, off, deg,
                out + (size_t)l * layer_elems);
        }
    } else {
        hipMemsetAsync(out + layer_elems, 0, 3 * layer_elems * sizeof(float), stream);
        const long long total_threads = (long long)E * 64;
        const int blocks = (int)((total_threads + 255) / 256);
        for (int l = 1; l <= 3; ++l) {
            spmm_atomic_kernel<<<blocks, 256, 0, stream>>>(
                out + (size_t)(l - 1) * layer_elems, ew, esrc, edst,
                out + (size_t)l * layer_elems, E);
        }
    }
}